// Round 12
// baseline (193.815 us; speedup 1.0000x reference)
//
#include <hip/hip_runtime.h>
#include <hip/hip_bf16.h>

#define BB 4
#define TT 4096
#define CC 1024
#define HH 64

// q is pre-scaled by 0.125*log2(e) at projection time; attn works in exp2 domain.
#define QSCALE 0.18033688011112042f
#define FIXMAX2 23.083120654223414f    // 16 * log2(e)

typedef __attribute__((ext_vector_type(8))) short short8;   // 8 x bf16 (4 VGPRs)
typedef __attribute__((ext_vector_type(8))) ushort ushortx8;
typedef __attribute__((ext_vector_type(4))) float floatx4;  // MFMA C/D

__device__ __forceinline__ ushort f2bf(float f) {
    union { float f; unsigned u; } a; a.f = f;
    const unsigned u = a.u;
    return (ushort)((u + 0x7fffu + ((u >> 16) & 1u)) >> 16);   // RNE
}
__device__ __forceinline__ float bf2f(ushort h) {
    union { unsigned u; float f; } a; a.u = ((unsigned)h) << 16; return a.f;
}

// ---------------------------------------------------------------------------
// Kernel A (v2): W [1024 x 64] f32 x3 -> wTf fragment-major bf16:
// wTf[(kc*24 + ks*12 + w*3 + j)*512 + lane*8 + e].  grid = 16 x 256.
// ---------------------------------------------------------------------------
__global__ __launch_bounds__(256)
void wtrans_kernel(const float* __restrict__ Wq, const float* __restrict__ Wk,
                   const float* __restrict__ Wv, ushort* __restrict__ wTf)
{
    const int tid = threadIdx.x;
    const int kc = blockIdx.x;
    #pragma unroll
    for (int it = 0; it < 6; ++it) {
        const int s = it * 256 + tid;           // slot id in [0, 1536)
        const int lane = s & 63;
        const int t = s >> 6;                   // (ks*4 + w)*3 + j
        const int j = t % 3;
        const int qv = t / 3;                   // ks*4 + w
        const int wv = qv & 3, ks = qv >> 2;
        const int r = wv * 48 + j * 16 + (lane & 15);
        const int mat = r >> 6, n = r & 63;
        const int k0 = kc * 64 + ks * 32 + (lane >> 4) * 8;
        const float* W = (mat == 0) ? Wq : (mat == 1) ? Wk : Wv;
        ushortx8 o;
        #pragma unroll
        for (int e = 0; e < 8; ++e)
            o[e] = f2bf(W[(size_t)(k0 + e) * 64 + n]);
        *(ushortx8*)(wTf + ((size_t)(kc * 24 + t) * 64 + lane) * 8) = o;
    }
}

// ---------------------------------------------------------------------------
// Kernel B (v10, the R8-winner shape, byte-identical): B-fragments from
// L2-resident wTf into ping-pong registers; x via small double-buffered LDS.
// BM=32, grid 512, 12 MFMA/chunk/wave, VGPR=88.
// ---------------------------------------------------------------------------
__global__ __launch_bounds__(256)
void qkv_mfma_kernel(const float* __restrict__ x, const ushort* __restrict__ wTf,
                     const float* __restrict__ bq, const float* __restrict__ bk,
                     const float* __restrict__ bv,
                     ushort* __restrict__ q, ushort* __restrict__ k,
                     ushort* __restrict__ vT)
{
    __shared__ ushort xs[2][32 * 72];

    const int tid = threadIdx.x, w = tid >> 6, lane = tid & 63;
    const int m = lane & 15, quad = lane >> 4;
    const int row0 = blockIdx.x * 32;

    floatx4 acc[2][3];
    #pragma unroll
    for (int mi = 0; mi < 2; ++mi)
        #pragma unroll
        for (int j = 0; j < 3; ++j) acc[mi][j] = (floatx4){0.f, 0.f, 0.f, 0.f};

    // B-frag base for this (wave, lane): + kc*12288 + ks*6144 + j*512
    const ushort* gb = wTf + (size_t)w * 1536 + lane * 8;

    // x stage coords: thread stages row (tid>>3), cols seg*8..+7 (2 float4)
    const int xr = tid >> 3, xseg = tid & 7;
    const float* gx = x + (size_t)(row0 + xr) * CC + xseg * 8;

    short8 bcur[3][2], bnxt[3][2];

    // ---- prologue: B-frags for chunk 0, x stage chunk 0 ----
    #pragma unroll
    for (int j = 0; j < 3; ++j)
        #pragma unroll
        for (int ks_ = 0; ks_ < 2; ++ks_)
            bcur[j][ks_] = *(const short8*)(gb + ks_ * 6144 + j * 512);
    {
        const float4 xa = *(const float4*)(gx);
        const float4 xb = *(const float4*)(gx + 4);
        ushortx8 p;
        p[0] = f2bf(xa.x); p[1] = f2bf(xa.y); p[2] = f2bf(xa.z); p[3] = f2bf(xa.w);
        p[4] = f2bf(xb.x); p[5] = f2bf(xb.y); p[6] = f2bf(xb.z); p[7] = f2bf(xb.w);
        *(ushortx8*)(&xs[0][xr * 72 + xseg * 8]) = p;
    }
    __syncthreads();

    for (int kc = 0; kc < 16; ++kc) {
        const int cur = kc & 1;
        // ---- issue prefetch of chunk kc+1: x (HBM, long) first, then B (L2) ----
        float4 na, nb;
        if (kc < 15) {
            const int k0n = (kc + 1) * 64;
            na = *(const float4*)(gx + k0n);
            nb = *(const float4*)(gx + k0n + 4);
            const ushort* gn = gb + (size_t)(kc + 1) * 12288;
            #pragma unroll
            for (int j = 0; j < 3; ++j)
                #pragma unroll
                for (int ks_ = 0; ks_ < 2; ++ks_)
                    bnxt[j][ks_] = *(const short8*)(gn + ks_ * 6144 + j * 512);
        }
        // ---- compute chunk kc ----
        const ushort* xb_ = xs[cur];
        #pragma unroll
        for (int mi = 0; mi < 2; ++mi) {
            const short8 a0 = *(const short8*)(xb_ + (mi * 16 + m) * 72 + quad * 8);
            const short8 a1 = *(const short8*)(xb_ + (mi * 16 + m) * 72 + 32 + quad * 8);
            #pragma unroll
            for (int j = 0; j < 3; ++j) {
                acc[mi][j] = __builtin_amdgcn_mfma_f32_16x16x32_bf16(a0, bcur[j][0], acc[mi][j], 0, 0, 0);
                acc[mi][j] = __builtin_amdgcn_mfma_f32_16x16x32_bf16(a1, bcur[j][1], acc[mi][j], 0, 0, 0);
            }
        }
        // ---- late half of x stage + B reg ping-pong ----
        if (kc < 15) {
            ushortx8 p;
            p[0] = f2bf(na.x); p[1] = f2bf(na.y); p[2] = f2bf(na.z); p[3] = f2bf(na.w);
            p[4] = f2bf(nb.x); p[5] = f2bf(nb.y); p[6] = f2bf(nb.z); p[7] = f2bf(nb.w);
            *(ushortx8*)(&xs[cur ^ 1][xr * 72 + xseg * 8]) = p;
            #pragma unroll
            for (int j = 0; j < 3; ++j) {
                bcur[j][0] = bnxt[j][0];
                bcur[j][1] = bnxt[j][1];
            }
        }
        __syncthreads();
    }

    // epilogue.  C-layout: row = quad*4 + r, col = nt*16 + m (nt = 3w + j).
    const int b_ = row0 >> 12, tb = row0 & (TT - 1);
    #pragma unroll
    for (int j = 0; j < 3; ++j) {
        const int nt = w * 3 + j;
        const int mat = nt >> 2;
        const int c = (nt & 3) * 16 + m;
        const float bias = (mat == 0) ? bq[c] : (mat == 1) ? bk[c] : bv[c];
        #pragma unroll
        for (int mi = 0; mi < 2; ++mi) {
            const int gr0 = row0 + mi * 16 + quad * 4;
            if (mat == 0) {
                #pragma unroll
                for (int r = 0; r < 4; ++r)
                    q[(size_t)(gr0 + r) * HH + c] = f2bf((acc[mi][j][r] + bias) * QSCALE);
            } else if (mat == 1) {
                #pragma unroll
                for (int r = 0; r < 4; ++r)
                    k[(size_t)(gr0 + r) * HH + c] = f2bf(acc[mi][j][r] + bias);
            } else {
                ushort4 pv;
                pv.x = f2bf(acc[mi][j][0] + bias); pv.y = f2bf(acc[mi][j][1] + bias);
                pv.z = f2bf(acc[mi][j][2] + bias); pv.w = f2bf(acc[mi][j][3] + bias);
                const int t0 = tb + mi * 16 + quad * 4;
                *(ushort4*)(vT + ((size_t)b_ * HH + c) * TT + t0) = pv;
            }
        }
    }
}

// ---------------------------------------------------------------------------
// Kernel C (v13 = R8's v11 with LDS strides 72->68).  Schedule, registers,
// masks, setprio: byte-identical to the banked winner.  The ONLY change:
// ks/vs/ps leading stride 68 instead of 72, shrinking LDS 27648->26112 B so
// residency rises 5 -> 6 blocks/CU (20 -> 24 waves/CU, +20% TLP -- the one
// mechanism that has consistently paid in this latency-bound kernel).
// Bank math at stride 68 (34 dwords/row): for all access patterns bank =
// (2m + 4*quad + 16*ks) mod 32 -> <=2 lanes/bank; 2-way is free (m136).
// grid = 4*64*8 = 2048 blocks x 256 thr.
// ---------------------------------------------------------------------------
#define AST 68
__global__ __launch_bounds__(256)
void attn_mfma_kernel(const ushort* __restrict__ q, const ushort* __restrict__ k,
                      const ushort* __restrict__ vT,
                      float* __restrict__ partL, ushort* __restrict__ partO)
{
    __shared__ ushort ks[64 * AST];
    __shared__ ushort vs[64 * AST];       // [d][s] (from vT)
    __shared__ ushort ps[4][16 * AST];    // wave-private P

    const int tid = threadIdx.x, w = tid >> 6, lane = tid & 63;
    const int m = lane & 15, quad = lane >> 4;
    const int pid = blockIdx.x;
    const int job = pid >> 3, split = pid & 7;
    const int b = job >> 6, tile = job & 63;
    const int i0 = tile * 64;
    const int nch = tile + 1;
    const int lo = (nch * split) >> 3, hi = (nch * (split + 1)) >> 3;

    const size_t qrow = ((size_t)b * TT + i0 + w * 16 + m) * HH;
    const uint4 aq0u = *(const uint4*)(q + qrow + quad * 8);
    const uint4 aq1u = *(const uint4*)(q + qrow + 32 + quad * 8);
    const short8 aq0 = *(const short8*)&aq0u;
    const short8 aq1 = *(const short8*)&aq1u;

    float lrow[4] = {0.f, 0.f, 0.f, 0.f};
    floatx4 oacc[4];
    #pragma unroll
    for (int nt = 0; nt < 4; ++nt) oacc[nt] = (floatx4){0.f, 0.f, 0.f, 0.f};

    const int iq0 = i0 + w * 16;
    for (int ch = lo; ch < hi; ++ch) {
        const int s0 = ch * 64;
        __syncthreads();
        const size_t kb = ((size_t)b * TT + s0) * HH;
        #pragma unroll
        for (int it = 0; it < 2; ++it) {
            const int t2 = it * 256 + tid;
            const int r = t2 >> 3, seg = t2 & 7;
            *(uint4*)(ks + r * AST + seg * 8) = *(const uint4*)(k + kb + (size_t)r * HH + seg * 8);
            *(uint4*)(vs + r * AST + seg * 8) = *(const uint4*)(vT + ((size_t)b * HH + r) * TT + s0 + seg * 8);
        }
        __syncthreads();

        floatx4 sc[4];
        __builtin_amdgcn_s_setprio(1);
        #pragma unroll
        for (int nt = 0; nt < 4; ++nt) {
            const short8 b0 = *(const short8*)(ks + (nt * 16 + m) * AST + quad * 8);
            const short8 b1 = *(const short8*)(ks + (nt * 16 + m) * AST + 32 + quad * 8);
            floatx4 s_ = (floatx4){0.f, 0.f, 0.f, 0.f};
            s_ = __builtin_amdgcn_mfma_f32_16x16x32_bf16(aq0, b0, s_, 0, 0, 0);
            s_ = __builtin_amdgcn_mfma_f32_16x16x32_bf16(aq1, b1, s_, 0, 0, 0);
            sc[nt] = s_;
        }
        __builtin_amdgcn_s_setprio(0);

        // fixed-max exp2-domain softmax.  p = 2^(s' - FIXMAX2); masked -> 0.
        const bool need_mask = (s0 + 63 > iq0);     // wave-uniform: diagonal chunk only
        #pragma unroll
        for (int r = 0; r < 4; ++r) {
            float t0 = sc[0][r] - FIXMAX2;
            float t1 = sc[1][r] - FIXMAX2;
            float t2 = sc[2][r] - FIXMAX2;
            float t3 = sc[3][r] - FIXMAX2;
            if (need_mask) {
                const int dlim = iq0 + quad * 4 + r - s0 - m;   // mask iff c*16 > dlim
                if (0  > dlim) t0 = -1e30f;
                if (16 > dlim) t1 = -1e30f;
                if (32 > dlim) t2 = -1e30f;
                if (48 > dlim) t3 = -1e30f;
            }
            const float p0 = __builtin_amdgcn_exp2f(t0);
            const float p1 = __builtin_amdgcn_exp2f(t1);
            const float p2 = __builtin_amdgcn_exp2f(t2);
            const float p3 = __builtin_amdgcn_exp2f(t3);
            lrow[r] += (p0 + p1) + (p2 + p3);
            ushort* pr = ps[w] + (quad * 4 + r) * AST;
            pr[m]      = f2bf(p0);
            pr[16 + m] = f2bf(p1);
            pr[32 + m] = f2bf(p2);
            pr[48 + m] = f2bf(p3);
        }

        // PV: A = P (LDS round-trip), B = vT rows
        __builtin_amdgcn_s_setprio(1);
        #pragma unroll
        for (int ks_ = 0; ks_ < 2; ++ks_) {
            const short8 ap = *(const short8*)(ps[w] + m * AST + ks_ * 32 + quad * 8);
            #pragma unroll
            for (int nt = 0; nt < 4; ++nt) {
                const short8 bv_ = *(const short8*)(vs + (nt * 16 + m) * AST + ks_ * 32 + quad * 8);
                oacc[nt] = __builtin_amdgcn_mfma_f32_16x16x32_bf16(ap, bv_, oacc[nt], 0, 0, 0);
            }
        }
        __builtin_amdgcn_s_setprio(0);
    }

    // reduce lrow across the 16 m-lanes (rows live in (quad, r))
    #pragma unroll
    for (int r = 0; r < 4; ++r) {
        float s = lrow[r];
        s += __shfl_xor(s, 1); s += __shfl_xor(s, 2);
        s += __shfl_xor(s, 4); s += __shfl_xor(s, 8);
        lrow[r] = s;
    }
    if (m == 0) {
        #pragma unroll
        for (int r = 0; r < 4; ++r)
            partL[(size_t)pid * 64 + w * 16 + quad * 4 + r] = lrow[r];
    }
    ushort* po = partO + ((size_t)pid * 64 + w * 16) * 64;
    #pragma unroll
    for (int r = 0; r < 4; ++r) {
        const int row = quad * 4 + r;
        #pragma unroll
        for (int nt = 0; nt < 4; ++nt)
            po[row * 64 + nt * 16 + m] = f2bf(oacc[nt][r]);
    }
}

// ---------------------------------------------------------------------------
// Kernel D (v2, unchanged): combine 8 split partials (shared fixed
// max -> plain sums).  grid = 256 (job), 256 threads.
// ---------------------------------------------------------------------------
__global__ __launch_bounds__(256)
void attn_combine_kernel(const float* __restrict__ partL,
                         const ushort* __restrict__ partO, float* __restrict__ out)
{
    const int job = blockIdx.x;
    const int tid = threadIdx.x;
    const int row = tid >> 2, dq = tid & 3;

    float L = 0.f;
    #pragma unroll
    for (int s = 0; s < 8; ++s) L += partL[(size_t)(job * 8 + s) * 64 + row];
    const float inv = 1.f / L;

    float o[16];
    #pragma unroll
    for (int i = 0; i < 16; ++i) o[i] = 0.f;
    #pragma unroll
    for (int s = 0; s < 8; ++s) {
        const ushort* po = partO + (((size_t)(job * 8 + s) * 64 + row) * 64 + dq * 16);
        #pragma unroll
        for (int i2 = 0; i2 < 2; ++i2) {
            const ushort4 pa = *(const ushort4*)(po + i2 * 8);
            const ushort4 pb = *(const ushort4*)(po + i2 * 8 + 4);
            o[i2*8+0] += bf2f(pa.x); o[i2*8+1] += bf2f(pa.y);
            o[i2*8+2] += bf2f(pa.z); o[i2*8+3] += bf2f(pa.w);
            o[i2*8+4] += bf2f(pb.x); o[i2*8+5] += bf2f(pb.y);
            o[i2*8+6] += bf2f(pb.z); o[i2*8+7] += bf2f(pb.w);
        }
    }
    float4* dst = (float4*)(out + ((size_t)job * 64 + row) * 64 + dq * 16);
    #pragma unroll
    for (int i = 0; i < 4; ++i) {
        float4 v; v.x = o[i*4]*inv; v.y = o[i*4+1]*inv; v.z = o[i*4+2]*inv; v.w = o[i*4+3]*inv;
        dst[i] = v;
    }
}

extern "C" void kernel_launch(void* const* d_in, const int* in_sizes, int n_in,
                              void* d_out, int out_size, void* d_ws, size_t ws_size,
                              hipStream_t stream) {
    (void)in_sizes; (void)n_in; (void)out_size; (void)ws_size;
    const float* x  = (const float*)d_in[0];
    // d_in[1] = causal mask, structural -> unused
    const float* Wq = (const float*)d_in[2];
    const float* bq = (const float*)d_in[3];
    const float* Wk = (const float*)d_in[4];
    const float* bk = (const float*)d_in[5];
    const float* Wv = (const float*)d_in[6];
    const float* bv = (const float*)d_in[7];
    float* out = (float*)d_out;

    char* ws = (char*)d_ws;
    ushort* wTf   = (ushort*)ws;                          // 384 KB @ 0
    ushort* qb    = (ushort*)(ws + 393216);               // 2 MB
    ushort* kb    = qb + (size_t)BB * TT * HH;            // 2 MB
    ushort* vTb   = kb + (size_t)BB * TT * HH;            // 2 MB
    float*  partL = (float*) (ws + 6684672);              // 512 KB (2048*64*4)
    ushort* partO = (ushort*)(ws + 7208960);              // 16.8 MB (total ~24 MB)

    wtrans_kernel   <<<16, 256, 0, stream>>>(Wq, Wk, Wv, wTf);
    qkv_mfma_kernel <<<(BB * TT) / 32, 256, 0, stream>>>(x, wTf, bq, bk, bv, qb, kb, vTb);
    attn_mfma_kernel<<<BB * 64 * 8, 256, 0, stream>>>(qb, kb, vTb, partL, partO);
    attn_combine_kernel<<<BB * 64, 256, 0, stream>>>(partL, partO, out);
}

// Round 13
// 191.184 us; speedup vs baseline: 1.0138x; 1.0138x over previous
//
#include <hip/hip_runtime.h>
#include <hip/hip_bf16.h>

#define BB 4
#define TT 4096
#define CC 1024
#define HH 64

// q is pre-scaled by 0.125*log2(e) at projection time; attn works in exp2 domain.
#define QSCALE 0.18033688011112042f
#define FIXMAX2 23.083120654223414f    // 16 * log2(e)

typedef __attribute__((ext_vector_type(8))) short short8;   // 8 x bf16 (4 VGPRs)
typedef __attribute__((ext_vector_type(8))) ushort ushortx8;
typedef __attribute__((ext_vector_type(4))) float floatx4;  // MFMA C/D

__device__ __forceinline__ ushort f2bf(float f) {
    union { float f; unsigned u; } a; a.f = f;
    const unsigned u = a.u;
    return (ushort)((u + 0x7fffu + ((u >> 16) & 1u)) >> 16);   // RNE
}
__device__ __forceinline__ float bf2f(ushort h) {
    union { unsigned u; float f; } a; a.u = ((unsigned)h) << 16; return a.f;
}

// ---------------------------------------------------------------------------
// Kernel A (v2): W [1024 x 64] f32 x3 -> wTf fragment-major bf16:
// wTf[(kc*24 + ks*12 + w*3 + j)*512 + lane*8 + e].  grid = 16 x 256.
// ---------------------------------------------------------------------------
__global__ __launch_bounds__(256)
void wtrans_kernel(const float* __restrict__ Wq, const float* __restrict__ Wk,
                   const float* __restrict__ Wv, ushort* __restrict__ wTf)
{
    const int tid = threadIdx.x;
    const int kc = blockIdx.x;
    #pragma unroll
    for (int it = 0; it < 6; ++it) {
        const int s = it * 256 + tid;           // slot id in [0, 1536)
        const int lane = s & 63;
        const int t = s >> 6;                   // (ks*4 + w)*3 + j
        const int j = t % 3;
        const int qv = t / 3;                   // ks*4 + w
        const int wv = qv & 3, ks = qv >> 2;
        const int r = wv * 48 + j * 16 + (lane & 15);
        const int mat = r >> 6, n = r & 63;
        const int k0 = kc * 64 + ks * 32 + (lane >> 4) * 8;
        const float* W = (mat == 0) ? Wq : (mat == 1) ? Wk : Wv;
        ushortx8 o;
        #pragma unroll
        for (int e = 0; e < 8; ++e)
            o[e] = f2bf(W[(size_t)(k0 + e) * 64 + n]);
        *(ushortx8*)(wTf + ((size_t)(kc * 24 + t) * 64 + lane) * 8) = o;
    }
}

// ---------------------------------------------------------------------------
// Kernel B (v10, the R8/R11-winner shape, byte-identical): B-fragments from
// L2-resident wTf into ping-pong registers; x via small double-buffered LDS.
// BM=32, grid 512, 12 MFMA/chunk/wave, VGPR=88 (the only shape where the
// ping-pong survives regalloc -- R4/R9 falsified smaller variants).
// ---------------------------------------------------------------------------
__global__ __launch_bounds__(256)
void qkv_mfma_kernel(const float* __restrict__ x, const ushort* __restrict__ wTf,
                     const float* __restrict__ bq, const float* __restrict__ bk,
                     const float* __restrict__ bv,
                     ushort* __restrict__ q, ushort* __restrict__ k,
                     ushort* __restrict__ vT)
{
    __shared__ ushort xs[2][32 * 72];

    const int tid = threadIdx.x, w = tid >> 6, lane = tid & 63;
    const int m = lane & 15, quad = lane >> 4;
    const int row0 = blockIdx.x * 32;

    floatx4 acc[2][3];
    #pragma unroll
    for (int mi = 0; mi < 2; ++mi)
        #pragma unroll
        for (int j = 0; j < 3; ++j) acc[mi][j] = (floatx4){0.f, 0.f, 0.f, 0.f};

    // B-frag base for this (wave, lane): + kc*12288 + ks*6144 + j*512
    const ushort* gb = wTf + (size_t)w * 1536 + lane * 8;

    // x stage coords: thread stages row (tid>>3), cols seg*8..+7 (2 float4)
    const int xr = tid >> 3, xseg = tid & 7;
    const float* gx = x + (size_t)(row0 + xr) * CC + xseg * 8;

    short8 bcur[3][2], bnxt[3][2];

    // ---- prologue: B-frags for chunk 0, x stage chunk 0 ----
    #pragma unroll
    for (int j = 0; j < 3; ++j)
        #pragma unroll
        for (int ks_ = 0; ks_ < 2; ++ks_)
            bcur[j][ks_] = *(const short8*)(gb + ks_ * 6144 + j * 512);
    {
        const float4 xa = *(const float4*)(gx);
        const float4 xb = *(const float4*)(gx + 4);
        ushortx8 p;
        p[0] = f2bf(xa.x); p[1] = f2bf(xa.y); p[2] = f2bf(xa.z); p[3] = f2bf(xa.w);
        p[4] = f2bf(xb.x); p[5] = f2bf(xb.y); p[6] = f2bf(xb.z); p[7] = f2bf(xb.w);
        *(ushortx8*)(&xs[0][xr * 72 + xseg * 8]) = p;
    }
    __syncthreads();

    for (int kc = 0; kc < 16; ++kc) {
        const int cur = kc & 1;
        // ---- issue prefetch of chunk kc+1: x (HBM, long) first, then B (L2) ----
        float4 na, nb;
        if (kc < 15) {
            const int k0n = (kc + 1) * 64;
            na = *(const float4*)(gx + k0n);
            nb = *(const float4*)(gx + k0n + 4);
            const ushort* gn = gb + (size_t)(kc + 1) * 12288;
            #pragma unroll
            for (int j = 0; j < 3; ++j)
                #pragma unroll
                for (int ks_ = 0; ks_ < 2; ++ks_)
                    bnxt[j][ks_] = *(const short8*)(gn + ks_ * 6144 + j * 512);
        }
        // ---- compute chunk kc ----
        const ushort* xb_ = xs[cur];
        #pragma unroll
        for (int mi = 0; mi < 2; ++mi) {
            const short8 a0 = *(const short8*)(xb_ + (mi * 16 + m) * 72 + quad * 8);
            const short8 a1 = *(const short8*)(xb_ + (mi * 16 + m) * 72 + 32 + quad * 8);
            #pragma unroll
            for (int j = 0; j < 3; ++j) {
                acc[mi][j] = __builtin_amdgcn_mfma_f32_16x16x32_bf16(a0, bcur[j][0], acc[mi][j], 0, 0, 0);
                acc[mi][j] = __builtin_amdgcn_mfma_f32_16x16x32_bf16(a1, bcur[j][1], acc[mi][j], 0, 0, 0);
            }
        }
        // ---- late half of x stage + B reg ping-pong ----
        if (kc < 15) {
            ushortx8 p;
            p[0] = f2bf(na.x); p[1] = f2bf(na.y); p[2] = f2bf(na.z); p[3] = f2bf(na.w);
            p[4] = f2bf(nb.x); p[5] = f2bf(nb.y); p[6] = f2bf(nb.z); p[7] = f2bf(nb.w);
            *(ushortx8*)(&xs[cur ^ 1][xr * 72 + xseg * 8]) = p;
            #pragma unroll
            for (int j = 0; j < 3; ++j) {
                bcur[j][0] = bnxt[j][0];
                bcur[j][1] = bnxt[j][1];
            }
        }
        __syncthreads();
    }

    // epilogue.  C-layout: row = quad*4 + r, col = nt*16 + m (nt = 3w + j).
    const int b_ = row0 >> 12, tb = row0 & (TT - 1);
    #pragma unroll
    for (int j = 0; j < 3; ++j) {
        const int nt = w * 3 + j;
        const int mat = nt >> 2;
        const int c = (nt & 3) * 16 + m;
        const float bias = (mat == 0) ? bq[c] : (mat == 1) ? bk[c] : bv[c];
        #pragma unroll
        for (int mi = 0; mi < 2; ++mi) {
            const int gr0 = row0 + mi * 16 + quad * 4;
            if (mat == 0) {
                #pragma unroll
                for (int r = 0; r < 4; ++r)
                    q[(size_t)(gr0 + r) * HH + c] = f2bf((acc[mi][j][r] + bias) * QSCALE);
            } else if (mat == 1) {
                #pragma unroll
                for (int r = 0; r < 4; ++r)
                    k[(size_t)(gr0 + r) * HH + c] = f2bf(acc[mi][j][r] + bias);
            } else {
                ushort4 pv;
                pv.x = f2bf(acc[mi][j][0] + bias); pv.y = f2bf(acc[mi][j][1] + bias);
                pv.z = f2bf(acc[mi][j][2] + bias); pv.w = f2bf(acc[mi][j][3] + bias);
                const int t0 = tb + mi * 16 + quad * 4;
                *(ushort4*)(vT + ((size_t)b_ * HH + c) * TT + t0) = pv;
            }
        }
    }
}

// ---------------------------------------------------------------------------
// Kernel C (v11 = v7 + setprio, the R8/R11 winner, banked at 191.5us total).
// Single-chunk LDS staging between two barriers, stride 72 (R12 falsified
// stride-68; R10 falsified paired staging; R5/R7 falsified reg-prefetch);
// T5 setprio around the MFMA clusters (+~4us, R8 A/B).
// grid = 4*64*8 = 2048 blocks x 256 thr.
// ---------------------------------------------------------------------------
__global__ __launch_bounds__(256)
void attn_mfma_kernel(const ushort* __restrict__ q, const ushort* __restrict__ k,
                      const ushort* __restrict__ vT,
                      float* __restrict__ partL, ushort* __restrict__ partO)
{
    __shared__ ushort ks[64 * 72];
    __shared__ ushort vs[64 * 72];        // [d][s] (from vT)
    __shared__ ushort ps[4][16 * 72];     // wave-private P

    const int tid = threadIdx.x, w = tid >> 6, lane = tid & 63;
    const int m = lane & 15, quad = lane >> 4;
    const int pid = blockIdx.x;
    const int job = pid >> 3, split = pid & 7;
    const int b = job >> 6, tile = job & 63;
    const int i0 = tile * 64;
    const int nch = tile + 1;
    const int lo = (nch * split) >> 3, hi = (nch * (split + 1)) >> 3;

    const size_t qrow = ((size_t)b * TT + i0 + w * 16 + m) * HH;
    const uint4 aq0u = *(const uint4*)(q + qrow + quad * 8);
    const uint4 aq1u = *(const uint4*)(q + qrow + 32 + quad * 8);
    const short8 aq0 = *(const short8*)&aq0u;
    const short8 aq1 = *(const short8*)&aq1u;

    float lrow[4] = {0.f, 0.f, 0.f, 0.f};
    floatx4 oacc[4];
    #pragma unroll
    for (int nt = 0; nt < 4; ++nt) oacc[nt] = (floatx4){0.f, 0.f, 0.f, 0.f};

    const int iq0 = i0 + w * 16;
    for (int ch = lo; ch < hi; ++ch) {
        const int s0 = ch * 64;
        __syncthreads();
        const size_t kb = ((size_t)b * TT + s0) * HH;
        #pragma unroll
        for (int it = 0; it < 2; ++it) {
            const int t2 = it * 256 + tid;
            const int r = t2 >> 3, seg = t2 & 7;
            *(uint4*)(ks + r * 72 + seg * 8) = *(const uint4*)(k + kb + (size_t)r * HH + seg * 8);
            *(uint4*)(vs + r * 72 + seg * 8) = *(const uint4*)(vT + ((size_t)b * HH + r) * TT + s0 + seg * 8);
        }
        __syncthreads();

        floatx4 sc[4];
        __builtin_amdgcn_s_setprio(1);
        #pragma unroll
        for (int nt = 0; nt < 4; ++nt) {
            const short8 b0 = *(const short8*)(ks + (nt * 16 + m) * 72 + quad * 8);
            const short8 b1 = *(const short8*)(ks + (nt * 16 + m) * 72 + 32 + quad * 8);
            floatx4 s_ = (floatx4){0.f, 0.f, 0.f, 0.f};
            s_ = __builtin_amdgcn_mfma_f32_16x16x32_bf16(aq0, b0, s_, 0, 0, 0);
            s_ = __builtin_amdgcn_mfma_f32_16x16x32_bf16(aq1, b1, s_, 0, 0, 0);
            sc[nt] = s_;
        }
        __builtin_amdgcn_s_setprio(0);

        // fixed-max exp2-domain softmax.  p = 2^(s' - FIXMAX2); masked -> 0.
        const bool need_mask = (s0 + 63 > iq0);     // wave-uniform: diagonal chunk only
        #pragma unroll
        for (int r = 0; r < 4; ++r) {
            float t0 = sc[0][r] - FIXMAX2;
            float t1 = sc[1][r] - FIXMAX2;
            float t2 = sc[2][r] - FIXMAX2;
            float t3 = sc[3][r] - FIXMAX2;
            if (need_mask) {
                const int dlim = iq0 + quad * 4 + r - s0 - m;   // mask iff c*16 > dlim
                if (0  > dlim) t0 = -1e30f;
                if (16 > dlim) t1 = -1e30f;
                if (32 > dlim) t2 = -1e30f;
                if (48 > dlim) t3 = -1e30f;
            }
            const float p0 = __builtin_amdgcn_exp2f(t0);
            const float p1 = __builtin_amdgcn_exp2f(t1);
            const float p2 = __builtin_amdgcn_exp2f(t2);
            const float p3 = __builtin_amdgcn_exp2f(t3);
            lrow[r] += (p0 + p1) + (p2 + p3);
            ushort* pr = ps[w] + (quad * 4 + r) * 72;
            pr[m]      = f2bf(p0);
            pr[16 + m] = f2bf(p1);
            pr[32 + m] = f2bf(p2);
            pr[48 + m] = f2bf(p3);
        }

        // PV: A = P (LDS round-trip), B = vT rows
        __builtin_amdgcn_s_setprio(1);
        #pragma unroll
        for (int ks_ = 0; ks_ < 2; ++ks_) {
            const short8 ap = *(const short8*)(ps[w] + m * 72 + ks_ * 32 + quad * 8);
            #pragma unroll
            for (int nt = 0; nt < 4; ++nt) {
                const short8 bv_ = *(const short8*)(vs + (nt * 16 + m) * 72 + ks_ * 32 + quad * 8);
                oacc[nt] = __builtin_amdgcn_mfma_f32_16x16x32_bf16(ap, bv_, oacc[nt], 0, 0, 0);
            }
        }
        __builtin_amdgcn_s_setprio(0);
    }

    // reduce lrow across the 16 m-lanes (rows live in (quad, r))
    #pragma unroll
    for (int r = 0; r < 4; ++r) {
        float s = lrow[r];
        s += __shfl_xor(s, 1); s += __shfl_xor(s, 2);
        s += __shfl_xor(s, 4); s += __shfl_xor(s, 8);
        lrow[r] = s;
    }
    if (m == 0) {
        #pragma unroll
        for (int r = 0; r < 4; ++r)
            partL[(size_t)pid * 64 + w * 16 + quad * 4 + r] = lrow[r];
    }
    ushort* po = partO + ((size_t)pid * 64 + w * 16) * 64;
    #pragma unroll
    for (int r = 0; r < 4; ++r) {
        const int row = quad * 4 + r;
        #pragma unroll
        for (int nt = 0; nt < 4; ++nt)
            po[row * 64 + nt * 16 + m] = f2bf(oacc[nt][r]);
    }
}

// ---------------------------------------------------------------------------
// Kernel D (v2, unchanged): combine 8 split partials (shared fixed
// max -> plain sums).  grid = 256 (job), 256 threads.
// ---------------------------------------------------------------------------
__global__ __launch_bounds__(256)
void attn_combine_kernel(const float* __restrict__ partL,
                         const ushort* __restrict__ partO, float* __restrict__ out)
{
    const int job = blockIdx.x;
    const int tid = threadIdx.x;
    const int row = tid >> 2, dq = tid & 3;

    float L = 0.f;
    #pragma unroll
    for (int s = 0; s < 8; ++s) L += partL[(size_t)(job * 8 + s) * 64 + row];
    const float inv = 1.f / L;

    float o[16];
    #pragma unroll
    for (int i = 0; i < 16; ++i) o[i] = 0.f;
    #pragma unroll
    for (int s = 0; s < 8; ++s) {
        const ushort* po = partO + (((size_t)(job * 8 + s) * 64 + row) * 64 + dq * 16);
        #pragma unroll
        for (int i2 = 0; i2 < 2; ++i2) {
            const ushort4 pa = *(const ushort4*)(po + i2 * 8);
            const ushort4 pb = *(const ushort4*)(po + i2 * 8 + 4);
            o[i2*8+0] += bf2f(pa.x); o[i2*8+1] += bf2f(pa.y);
            o[i2*8+2] += bf2f(pa.z); o[i2*8+3] += bf2f(pa.w);
            o[i2*8+4] += bf2f(pb.x); o[i2*8+5] += bf2f(pb.y);
            o[i2*8+6] += bf2f(pb.z); o[i2*8+7] += bf2f(pb.w);
        }
    }
    float4* dst = (float4*)(out + ((size_t)job * 64 + row) * 64 + dq * 16);
    #pragma unroll
    for (int i = 0; i < 4; ++i) {
        float4 v; v.x = o[i*4]*inv; v.y = o[i*4+1]*inv; v.z = o[i*4+2]*inv; v.w = o[i*4+3]*inv;
        dst[i] = v;
    }
}

extern "C" void kernel_launch(void* const* d_in, const int* in_sizes, int n_in,
                              void* d_out, int out_size, void* d_ws, size_t ws_size,
                              hipStream_t stream) {
    (void)in_sizes; (void)n_in; (void)out_size; (void)ws_size;
    const float* x  = (const float*)d_in[0];
    // d_in[1] = causal mask, structural -> unused
    const float* Wq = (const float*)d_in[2];
    const float* bq = (const float*)d_in[3];
    const float* Wk = (const float*)d_in[4];
    const float* bk = (const float*)d_in[5];
    const float* Wv = (const float*)d_in[6];
    const float* bv = (const float*)d_in[7];
    float* out = (float*)d_out;

    char* ws = (char*)d_ws;
    ushort* wTf   = (ushort*)ws;                          // 384 KB @ 0
    ushort* qb    = (ushort*)(ws + 393216);               // 2 MB
    ushort* kb    = qb + (size_t)BB * TT * HH;            // 2 MB
    ushort* vTb   = kb + (size_t)BB * TT * HH;            // 2 MB
    float*  partL = (float*) (ws + 6684672);              // 512 KB (2048*64*4)
    ushort* partO = (ushort*)(ws + 7208960);              // 16.8 MB (total ~24 MB)

    wtrans_kernel   <<<16, 256, 0, stream>>>(Wq, Wk, Wv, wTf);
    qkv_mfma_kernel <<<(BB * TT) / 32, 256, 0, stream>>>(x, wTf, bq, bk, bv, qb, kb, vTb);
    attn_mfma_kernel<<<BB * 64 * 8, 256, 0, stream>>>(qb, kb, vTb, partL, partO);
    attn_combine_kernel<<<BB * 64, 256, 0, stream>>>(partL, partO, out);
}

// Round 14
// 189.833 us; speedup vs baseline: 1.0210x; 1.0071x over previous
//
#include <hip/hip_runtime.h>
#include <hip/hip_bf16.h>

#define BB 4
#define TT 4096
#define CC 1024
#define HH 64

// q is pre-scaled by 0.125*log2(e) at projection time; attn works in exp2 domain.
#define QSCALE 0.18033688011112042f
#define FIXMAX2 23.083120654223414f    // 16 * log2(e)

typedef __attribute__((ext_vector_type(8))) short short8;   // 8 x bf16 (4 VGPRs)
typedef __attribute__((ext_vector_type(8))) ushort ushortx8;
typedef __attribute__((ext_vector_type(4))) float floatx4;  // MFMA C/D

__device__ __forceinline__ ushort f2bf(float f) {
    union { float f; unsigned u; } a; a.f = f;
    const unsigned u = a.u;
    return (ushort)((u + 0x7fffu + ((u >> 16) & 1u)) >> 16);   // RNE
}
__device__ __forceinline__ float bf2f(ushort h) {
    union { unsigned u; float f; } a; a.u = ((unsigned)h) << 16; return a.f;
}

// ---------------------------------------------------------------------------
// Kernel A (v2): W [1024 x 64] f32 x3 -> wTf fragment-major bf16:
// wTf[(kc*24 + ks*12 + w*3 + j)*512 + lane*8 + e].  grid = 16 x 256.
// ---------------------------------------------------------------------------
__global__ __launch_bounds__(256)
void wtrans_kernel(const float* __restrict__ Wq, const float* __restrict__ Wk,
                   const float* __restrict__ Wv, ushort* __restrict__ wTf)
{
    const int tid = threadIdx.x;
    const int kc = blockIdx.x;
    #pragma unroll
    for (int it = 0; it < 6; ++it) {
        const int s = it * 256 + tid;           // slot id in [0, 1536)
        const int lane = s & 63;
        const int t = s >> 6;                   // (ks*4 + w)*3 + j
        const int j = t % 3;
        const int qv = t / 3;                   // ks*4 + w
        const int wv = qv & 3, ks = qv >> 2;
        const int r = wv * 48 + j * 16 + (lane & 15);
        const int mat = r >> 6, n = r & 63;
        const int k0 = kc * 64 + ks * 32 + (lane >> 4) * 8;
        const float* W = (mat == 0) ? Wq : (mat == 1) ? Wk : Wv;
        ushortx8 o;
        #pragma unroll
        for (int e = 0; e < 8; ++e)
            o[e] = f2bf(W[(size_t)(k0 + e) * 64 + n]);
        *(ushortx8*)(wTf + ((size_t)(kc * 24 + t) * 64 + lane) * 8) = o;
    }
}

// ---------------------------------------------------------------------------
// Kernel B (v10, the R8/R11-winner shape, byte-identical): B-fragments from
// L2-resident wTf into ping-pong registers; x via small double-buffered LDS.
// BM=32, grid 512, 12 MFMA/chunk/wave, VGPR=88.
// ---------------------------------------------------------------------------
__global__ __launch_bounds__(256)
void qkv_mfma_kernel(const float* __restrict__ x, const ushort* __restrict__ wTf,
                     const float* __restrict__ bq, const float* __restrict__ bk,
                     const float* __restrict__ bv,
                     ushort* __restrict__ q, ushort* __restrict__ k,
                     ushort* __restrict__ vT)
{
    __shared__ ushort xs[2][32 * 72];

    const int tid = threadIdx.x, w = tid >> 6, lane = tid & 63;
    const int m = lane & 15, quad = lane >> 4;
    const int row0 = blockIdx.x * 32;

    floatx4 acc[2][3];
    #pragma unroll
    for (int mi = 0; mi < 2; ++mi)
        #pragma unroll
        for (int j = 0; j < 3; ++j) acc[mi][j] = (floatx4){0.f, 0.f, 0.f, 0.f};

    // B-frag base for this (wave, lane): + kc*12288 + ks*6144 + j*512
    const ushort* gb = wTf + (size_t)w * 1536 + lane * 8;

    // x stage coords: thread stages row (tid>>3), cols seg*8..+7 (2 float4)
    const int xr = tid >> 3, xseg = tid & 7;
    const float* gx = x + (size_t)(row0 + xr) * CC + xseg * 8;

    short8 bcur[3][2], bnxt[3][2];

    // ---- prologue: B-frags for chunk 0, x stage chunk 0 ----
    #pragma unroll
    for (int j = 0; j < 3; ++j)
        #pragma unroll
        for (int ks_ = 0; ks_ < 2; ++ks_)
            bcur[j][ks_] = *(const short8*)(gb + ks_ * 6144 + j * 512);
    {
        const float4 xa = *(const float4*)(gx);
        const float4 xb = *(const float4*)(gx + 4);
        ushortx8 p;
        p[0] = f2bf(xa.x); p[1] = f2bf(xa.y); p[2] = f2bf(xa.z); p[3] = f2bf(xa.w);
        p[4] = f2bf(xb.x); p[5] = f2bf(xb.y); p[6] = f2bf(xb.z); p[7] = f2bf(xb.w);
        *(ushortx8*)(&xs[0][xr * 72 + xseg * 8]) = p;
    }
    __syncthreads();

    for (int kc = 0; kc < 16; ++kc) {
        const int cur = kc & 1;
        // ---- issue prefetch of chunk kc+1: x (HBM, long) first, then B (L2) ----
        float4 na, nb;
        if (kc < 15) {
            const int k0n = (kc + 1) * 64;
            na = *(const float4*)(gx + k0n);
            nb = *(const float4*)(gx + k0n + 4);
            const ushort* gn = gb + (size_t)(kc + 1) * 12288;
            #pragma unroll
            for (int j = 0; j < 3; ++j)
                #pragma unroll
                for (int ks_ = 0; ks_ < 2; ++ks_)
                    bnxt[j][ks_] = *(const short8*)(gn + ks_ * 6144 + j * 512);
        }
        // ---- compute chunk kc ----
        const ushort* xb_ = xs[cur];
        #pragma unroll
        for (int mi = 0; mi < 2; ++mi) {
            const short8 a0 = *(const short8*)(xb_ + (mi * 16 + m) * 72 + quad * 8);
            const short8 a1 = *(const short8*)(xb_ + (mi * 16 + m) * 72 + 32 + quad * 8);
            #pragma unroll
            for (int j = 0; j < 3; ++j) {
                acc[mi][j] = __builtin_amdgcn_mfma_f32_16x16x32_bf16(a0, bcur[j][0], acc[mi][j], 0, 0, 0);
                acc[mi][j] = __builtin_amdgcn_mfma_f32_16x16x32_bf16(a1, bcur[j][1], acc[mi][j], 0, 0, 0);
            }
        }
        // ---- late half of x stage + B reg ping-pong ----
        if (kc < 15) {
            ushortx8 p;
            p[0] = f2bf(na.x); p[1] = f2bf(na.y); p[2] = f2bf(na.z); p[3] = f2bf(na.w);
            p[4] = f2bf(nb.x); p[5] = f2bf(nb.y); p[6] = f2bf(nb.z); p[7] = f2bf(nb.w);
            *(ushortx8*)(&xs[cur ^ 1][xr * 72 + xseg * 8]) = p;
            #pragma unroll
            for (int j = 0; j < 3; ++j) {
                bcur[j][0] = bnxt[j][0];
                bcur[j][1] = bnxt[j][1];
            }
        }
        __syncthreads();
    }

    // epilogue.  C-layout: row = quad*4 + r, col = nt*16 + m (nt = 3w + j).
    const int b_ = row0 >> 12, tb = row0 & (TT - 1);
    #pragma unroll
    for (int j = 0; j < 3; ++j) {
        const int nt = w * 3 + j;
        const int mat = nt >> 2;
        const int c = (nt & 3) * 16 + m;
        const float bias = (mat == 0) ? bq[c] : (mat == 1) ? bk[c] : bv[c];
        #pragma unroll
        for (int mi = 0; mi < 2; ++mi) {
            const int gr0 = row0 + mi * 16 + quad * 4;
            if (mat == 0) {
                #pragma unroll
                for (int r = 0; r < 4; ++r)
                    q[(size_t)(gr0 + r) * HH + c] = f2bf((acc[mi][j][r] + bias) * QSCALE);
            } else if (mat == 1) {
                #pragma unroll
                for (int r = 0; r < 4; ++r)
                    k[(size_t)(gr0 + r) * HH + c] = f2bf(acc[mi][j][r] + bias);
            } else {
                ushort4 pv;
                pv.x = f2bf(acc[mi][j][0] + bias); pv.y = f2bf(acc[mi][j][1] + bias);
                pv.z = f2bf(acc[mi][j][2] + bias); pv.w = f2bf(acc[mi][j][3] + bias);
                const int t0 = tb + mi * 16 + quad * 4;
                *(ushort4*)(vT + ((size_t)b_ * HH + c) * TT + t0) = pv;
            }
        }
    }
}

// ---------------------------------------------------------------------------
// Kernel C (v14 = v11 + LPT job reorder).  Body byte-identical to the banked
// R8/R11 winner (stride-72 staging, 2 barriers, setprio).  ONLY change:
// tile' = 63 - (jobRaw & 63), so the heaviest causal jobs (tile=63, 8
// chunks/split, ~2x average) dispatch FIRST instead of last -- removing the
// scheduling tail where the final heavy blocks start only as slots free.
// Partials are written at the effective pid (bijection), so attn_combine is
// untouched.  grid = 4*64*8 = 2048 blocks x 256 thr.
// ---------------------------------------------------------------------------
__global__ __launch_bounds__(256)
void attn_mfma_kernel(const ushort* __restrict__ q, const ushort* __restrict__ k,
                      const ushort* __restrict__ vT,
                      float* __restrict__ partL, ushort* __restrict__ partO)
{
    __shared__ ushort ks[64 * 72];
    __shared__ ushort vs[64 * 72];        // [d][s] (from vT)
    __shared__ ushort ps[4][16 * 72];     // wave-private P

    const int tid = threadIdx.x, w = tid >> 6, lane = tid & 63;
    const int m = lane & 15, quad = lane >> 4;
    const int jobRaw = blockIdx.x >> 3, split = blockIdx.x & 7;
    const int b = jobRaw >> 6;
    const int tile = 63 - (jobRaw & 63);          // LPT: heavy tiles first
    const int job = (b << 6) | tile;              // effective job id
    const int pid = job * 8 + split;              // effective partial index
    const int i0 = tile * 64;
    const int nch = tile + 1;
    const int lo = (nch * split) >> 3, hi = (nch * (split + 1)) >> 3;

    const size_t qrow = ((size_t)b * TT + i0 + w * 16 + m) * HH;
    const uint4 aq0u = *(const uint4*)(q + qrow + quad * 8);
    const uint4 aq1u = *(const uint4*)(q + qrow + 32 + quad * 8);
    const short8 aq0 = *(const short8*)&aq0u;
    const short8 aq1 = *(const short8*)&aq1u;

    float lrow[4] = {0.f, 0.f, 0.f, 0.f};
    floatx4 oacc[4];
    #pragma unroll
    for (int nt = 0; nt < 4; ++nt) oacc[nt] = (floatx4){0.f, 0.f, 0.f, 0.f};

    const int iq0 = i0 + w * 16;
    for (int ch = lo; ch < hi; ++ch) {
        const int s0 = ch * 64;
        __syncthreads();
        const size_t kb = ((size_t)b * TT + s0) * HH;
        #pragma unroll
        for (int it = 0; it < 2; ++it) {
            const int t2 = it * 256 + tid;
            const int r = t2 >> 3, seg = t2 & 7;
            *(uint4*)(ks + r * 72 + seg * 8) = *(const uint4*)(k + kb + (size_t)r * HH + seg * 8);
            *(uint4*)(vs + r * 72 + seg * 8) = *(const uint4*)(vT + ((size_t)b * HH + r) * TT + s0 + seg * 8);
        }
        __syncthreads();

        floatx4 sc[4];
        __builtin_amdgcn_s_setprio(1);
        #pragma unroll
        for (int nt = 0; nt < 4; ++nt) {
            const short8 b0 = *(const short8*)(ks + (nt * 16 + m) * 72 + quad * 8);
            const short8 b1 = *(const short8*)(ks + (nt * 16 + m) * 72 + 32 + quad * 8);
            floatx4 s_ = (floatx4){0.f, 0.f, 0.f, 0.f};
            s_ = __builtin_amdgcn_mfma_f32_16x16x32_bf16(aq0, b0, s_, 0, 0, 0);
            s_ = __builtin_amdgcn_mfma_f32_16x16x32_bf16(aq1, b1, s_, 0, 0, 0);
            sc[nt] = s_;
        }
        __builtin_amdgcn_s_setprio(0);

        // fixed-max exp2-domain softmax.  p = 2^(s' - FIXMAX2); masked -> 0.
        const bool need_mask = (s0 + 63 > iq0);     // wave-uniform: diagonal chunk only
        #pragma unroll
        for (int r = 0; r < 4; ++r) {
            float t0 = sc[0][r] - FIXMAX2;
            float t1 = sc[1][r] - FIXMAX2;
            float t2 = sc[2][r] - FIXMAX2;
            float t3 = sc[3][r] - FIXMAX2;
            if (need_mask) {
                const int dlim = iq0 + quad * 4 + r - s0 - m;   // mask iff c*16 > dlim
                if (0  > dlim) t0 = -1e30f;
                if (16 > dlim) t1 = -1e30f;
                if (32 > dlim) t2 = -1e30f;
                if (48 > dlim) t3 = -1e30f;
            }
            const float p0 = __builtin_amdgcn_exp2f(t0);
            const float p1 = __builtin_amdgcn_exp2f(t1);
            const float p2 = __builtin_amdgcn_exp2f(t2);
            const float p3 = __builtin_amdgcn_exp2f(t3);
            lrow[r] += (p0 + p1) + (p2 + p3);
            ushort* pr = ps[w] + (quad * 4 + r) * 72;
            pr[m]      = f2bf(p0);
            pr[16 + m] = f2bf(p1);
            pr[32 + m] = f2bf(p2);
            pr[48 + m] = f2bf(p3);
        }

        // PV: A = P (LDS round-trip), B = vT rows
        __builtin_amdgcn_s_setprio(1);
        #pragma unroll
        for (int ks_ = 0; ks_ < 2; ++ks_) {
            const short8 ap = *(const short8*)(ps[w] + m * 72 + ks_ * 32 + quad * 8);
            #pragma unroll
            for (int nt = 0; nt < 4; ++nt) {
                const short8 bv_ = *(const short8*)(vs + (nt * 16 + m) * 72 + ks_ * 32 + quad * 8);
                oacc[nt] = __builtin_amdgcn_mfma_f32_16x16x32_bf16(ap, bv_, oacc[nt], 0, 0, 0);
            }
        }
        __builtin_amdgcn_s_setprio(0);
    }

    // reduce lrow across the 16 m-lanes (rows live in (quad, r))
    #pragma unroll
    for (int r = 0; r < 4; ++r) {
        float s = lrow[r];
        s += __shfl_xor(s, 1); s += __shfl_xor(s, 2);
        s += __shfl_xor(s, 4); s += __shfl_xor(s, 8);
        lrow[r] = s;
    }
    if (m == 0) {
        #pragma unroll
        for (int r = 0; r < 4; ++r)
            partL[(size_t)pid * 64 + w * 16 + quad * 4 + r] = lrow[r];
    }
    ushort* po = partO + ((size_t)pid * 64 + w * 16) * 64;
    #pragma unroll
    for (int r = 0; r < 4; ++r) {
        const int row = quad * 4 + r;
        #pragma unroll
        for (int nt = 0; nt < 4; ++nt)
            po[row * 64 + nt * 16 + m] = f2bf(oacc[nt][r]);
    }
}

// ---------------------------------------------------------------------------
// Kernel D (v2, unchanged): combine 8 split partials (shared fixed
// max -> plain sums).  grid = 256 (job), 256 threads.
// ---------------------------------------------------------------------------
__global__ __launch_bounds__(256)
void attn_combine_kernel(const float* __restrict__ partL,
                         const ushort* __restrict__ partO, float* __restrict__ out)
{
    const int job = blockIdx.x;
    const int tid = threadIdx.x;
    const int row = tid >> 2, dq = tid & 3;

    float L = 0.f;
    #pragma unroll
    for (int s = 0; s < 8; ++s) L += partL[(size_t)(job * 8 + s) * 64 + row];
    const float inv = 1.f / L;

    float o[16];
    #pragma unroll
    for (int i = 0; i < 16; ++i) o[i] = 0.f;
    #pragma unroll
    for (int s = 0; s < 8; ++s) {
        const ushort* po = partO + (((size_t)(job * 8 + s) * 64 + row) * 64 + dq * 16);
        #pragma unroll
        for (int i2 = 0; i2 < 2; ++i2) {
            const ushort4 pa = *(const ushort4*)(po + i2 * 8);
            const ushort4 pb = *(const ushort4*)(po + i2 * 8 + 4);
            o[i2*8+0] += bf2f(pa.x); o[i2*8+1] += bf2f(pa.y);
            o[i2*8+2] += bf2f(pa.z); o[i2*8+3] += bf2f(pa.w);
            o[i2*8+4] += bf2f(pb.x); o[i2*8+5] += bf2f(pb.y);
            o[i2*8+6] += bf2f(pb.z); o[i2*8+7] += bf2f(pb.w);
        }
    }
    float4* dst = (float4*)(out + ((size_t)job * 64 + row) * 64 + dq * 16);
    #pragma unroll
    for (int i = 0; i < 4; ++i) {
        float4 v; v.x = o[i*4]*inv; v.y = o[i*4+1]*inv; v.z = o[i*4+2]*inv; v.w = o[i*4+3]*inv;
        dst[i] = v;
    }
}

extern "C" void kernel_launch(void* const* d_in, const int* in_sizes, int n_in,
                              void* d_out, int out_size, void* d_ws, size_t ws_size,
                              hipStream_t stream) {
    (void)in_sizes; (void)n_in; (void)out_size; (void)ws_size;
    const float* x  = (const float*)d_in[0];
    // d_in[1] = causal mask, structural -> unused
    const float* Wq = (const float*)d_in[2];
    const float* bq = (const float*)d_in[3];
    const float* Wk = (const float*)d_in[4];
    const float* bk = (const float*)d_in[5];
    const float* Wv = (const float*)d_in[6];
    const float* bv = (const float*)d_in[7];
    float* out = (float*)d_out;

    char* ws = (char*)d_ws;
    ushort* wTf   = (ushort*)ws;                          // 384 KB @ 0
    ushort* qb    = (ushort*)(ws + 393216);               // 2 MB
    ushort* kb    = qb + (size_t)BB * TT * HH;            // 2 MB
    ushort* vTb   = kb + (size_t)BB * TT * HH;            // 2 MB
    float*  partL = (float*) (ws + 6684672);              // 512 KB (2048*64*4)
    ushort* partO = (ushort*)(ws + 7208960);              // 16.8 MB (total ~24 MB)

    wtrans_kernel   <<<16, 256, 0, stream>>>(Wq, Wk, Wv, wTf);
    qkv_mfma_kernel <<<(BB * TT) / 32, 256, 0, stream>>>(x, wTf, bq, bk, bv, qb, kb, vTb);
    attn_mfma_kernel<<<BB * 64 * 8, 256, 0, stream>>>(qb, kb, vTb, partL, partO);
    attn_combine_kernel<<<BB * 64, 256, 0, stream>>>(partL, partO, out);
}

// Round 15
// 186.811 us; speedup vs baseline: 1.0375x; 1.0162x over previous
//
#include <hip/hip_runtime.h>
#include <hip/hip_bf16.h>

#define BB 4
#define TT 4096
#define CC 1024
#define HH 64

// q is pre-scaled by 0.125*log2(e) at projection time; attn works in exp2 domain.
#define QSCALE 0.18033688011112042f
#define FIXMAX2 23.083120654223414f    // 16 * log2(e)

typedef __attribute__((ext_vector_type(8))) short short8;   // 8 x bf16 (4 VGPRs)
typedef __attribute__((ext_vector_type(8))) ushort ushortx8;
typedef __attribute__((ext_vector_type(4))) float floatx4;  // MFMA C/D

__device__ __forceinline__ ushort f2bf(float f) {
    union { float f; unsigned u; } a; a.f = f;
    const unsigned u = a.u;
    return (ushort)((u + 0x7fffu + ((u >> 16) & 1u)) >> 16);   // RNE
}
__device__ __forceinline__ float bf2f(ushort h) {
    union { unsigned u; float f; } a; a.u = ((unsigned)h) << 16; return a.f;
}

// ---------------------------------------------------------------------------
// Kernel A (v2): W [1024 x 64] f32 x3 -> wTf fragment-major bf16:
// wTf[(kc*24 + ks*12 + w*3 + j)*512 + lane*8 + e].  grid = 16 x 256.
// ---------------------------------------------------------------------------
__global__ __launch_bounds__(256)
void wtrans_kernel(const float* __restrict__ Wq, const float* __restrict__ Wk,
                   const float* __restrict__ Wv, ushort* __restrict__ wTf)
{
    const int tid = threadIdx.x;
    const int kc = blockIdx.x;
    #pragma unroll
    for (int it = 0; it < 6; ++it) {
        const int s = it * 256 + tid;           // slot id in [0, 1536)
        const int lane = s & 63;
        const int t = s >> 6;                   // (ks*4 + w)*3 + j
        const int j = t % 3;
        const int qv = t / 3;                   // ks*4 + w
        const int wv = qv & 3, ks = qv >> 2;
        const int r = wv * 48 + j * 16 + (lane & 15);
        const int mat = r >> 6, n = r & 63;
        const int k0 = kc * 64 + ks * 32 + (lane >> 4) * 8;
        const float* W = (mat == 0) ? Wq : (mat == 1) ? Wk : Wv;
        ushortx8 o;
        #pragma unroll
        for (int e = 0; e < 8; ++e)
            o[e] = f2bf(W[(size_t)(k0 + e) * 64 + n]);
        *(ushortx8*)(wTf + ((size_t)(kc * 24 + t) * 64 + lane) * 8) = o;
    }
}

// ---------------------------------------------------------------------------
// Kernel B (v10, the R8/R11/R14-winner shape, byte-identical): B-fragments
// from L2-resident wTf; x via small double-buffered LDS.  BM=32, grid 512,
// 12 MFMA/chunk/wave.  (R14 profile: allocator materializes this at VGPR=48
// -- ping-pong stripped -- perf carried by LDS-dbuf + TLP; R4/R9 showed
// forcing more registers doesn't pay.)
// ---------------------------------------------------------------------------
__global__ __launch_bounds__(256)
void qkv_mfma_kernel(const float* __restrict__ x, const ushort* __restrict__ wTf,
                     const float* __restrict__ bq, const float* __restrict__ bk,
                     const float* __restrict__ bv,
                     ushort* __restrict__ q, ushort* __restrict__ k,
                     ushort* __restrict__ vT)
{
    __shared__ ushort xs[2][32 * 72];

    const int tid = threadIdx.x, w = tid >> 6, lane = tid & 63;
    const int m = lane & 15, quad = lane >> 4;
    const int row0 = blockIdx.x * 32;

    floatx4 acc[2][3];
    #pragma unroll
    for (int mi = 0; mi < 2; ++mi)
        #pragma unroll
        for (int j = 0; j < 3; ++j) acc[mi][j] = (floatx4){0.f, 0.f, 0.f, 0.f};

    // B-frag base for this (wave, lane): + kc*12288 + ks*6144 + j*512
    const ushort* gb = wTf + (size_t)w * 1536 + lane * 8;

    // x stage coords: thread stages row (tid>>3), cols seg*8..+7 (2 float4)
    const int xr = tid >> 3, xseg = tid & 7;
    const float* gx = x + (size_t)(row0 + xr) * CC + xseg * 8;

    short8 bcur[3][2], bnxt[3][2];

    // ---- prologue: B-frags for chunk 0, x stage chunk 0 ----
    #pragma unroll
    for (int j = 0; j < 3; ++j)
        #pragma unroll
        for (int ks_ = 0; ks_ < 2; ++ks_)
            bcur[j][ks_] = *(const short8*)(gb + ks_ * 6144 + j * 512);
    {
        const float4 xa = *(const float4*)(gx);
        const float4 xb = *(const float4*)(gx + 4);
        ushortx8 p;
        p[0] = f2bf(xa.x); p[1] = f2bf(xa.y); p[2] = f2bf(xa.z); p[3] = f2bf(xa.w);
        p[4] = f2bf(xb.x); p[5] = f2bf(xb.y); p[6] = f2bf(xb.z); p[7] = f2bf(xb.w);
        *(ushortx8*)(&xs[0][xr * 72 + xseg * 8]) = p;
    }
    __syncthreads();

    for (int kc = 0; kc < 16; ++kc) {
        const int cur = kc & 1;
        // ---- issue prefetch of chunk kc+1: x (HBM, long) first, then B (L2) ----
        float4 na, nb;
        if (kc < 15) {
            const int k0n = (kc + 1) * 64;
            na = *(const float4*)(gx + k0n);
            nb = *(const float4*)(gx + k0n + 4);
            const ushort* gn = gb + (size_t)(kc + 1) * 12288;
            #pragma unroll
            for (int j = 0; j < 3; ++j)
                #pragma unroll
                for (int ks_ = 0; ks_ < 2; ++ks_)
                    bnxt[j][ks_] = *(const short8*)(gn + ks_ * 6144 + j * 512);
        }
        // ---- compute chunk kc ----
        const ushort* xb_ = xs[cur];
        #pragma unroll
        for (int mi = 0; mi < 2; ++mi) {
            const short8 a0 = *(const short8*)(xb_ + (mi * 16 + m) * 72 + quad * 8);
            const short8 a1 = *(const short8*)(xb_ + (mi * 16 + m) * 72 + 32 + quad * 8);
            #pragma unroll
            for (int j = 0; j < 3; ++j) {
                acc[mi][j] = __builtin_amdgcn_mfma_f32_16x16x32_bf16(a0, bcur[j][0], acc[mi][j], 0, 0, 0);
                acc[mi][j] = __builtin_amdgcn_mfma_f32_16x16x32_bf16(a1, bcur[j][1], acc[mi][j], 0, 0, 0);
            }
        }
        // ---- late half of x stage + B reg ping-pong ----
        if (kc < 15) {
            ushortx8 p;
            p[0] = f2bf(na.x); p[1] = f2bf(na.y); p[2] = f2bf(na.z); p[3] = f2bf(na.w);
            p[4] = f2bf(nb.x); p[5] = f2bf(nb.y); p[6] = f2bf(nb.z); p[7] = f2bf(nb.w);
            *(ushortx8*)(&xs[cur ^ 1][xr * 72 + xseg * 8]) = p;
            #pragma unroll
            for (int j = 0; j < 3; ++j) {
                bcur[j][0] = bnxt[j][0];
                bcur[j][1] = bnxt[j][1];
            }
        }
        __syncthreads();
    }

    // epilogue.  C-layout: row = quad*4 + r, col = nt*16 + m (nt = 3w + j).
    const int b_ = row0 >> 12, tb = row0 & (TT - 1);
    #pragma unroll
    for (int j = 0; j < 3; ++j) {
        const int nt = w * 3 + j;
        const int mat = nt >> 2;
        const int c = (nt & 3) * 16 + m;
        const float bias = (mat == 0) ? bq[c] : (mat == 1) ? bk[c] : bv[c];
        #pragma unroll
        for (int mi = 0; mi < 2; ++mi) {
            const int gr0 = row0 + mi * 16 + quad * 4;
            if (mat == 0) {
                #pragma unroll
                for (int r = 0; r < 4; ++r)
                    q[(size_t)(gr0 + r) * HH + c] = f2bf((acc[mi][j][r] + bias) * QSCALE);
            } else if (mat == 1) {
                #pragma unroll
                for (int r = 0; r < 4; ++r)
                    k[(size_t)(gr0 + r) * HH + c] = f2bf(acc[mi][j][r] + bias);
            } else {
                ushort4 pv;
                pv.x = f2bf(acc[mi][j][0] + bias); pv.y = f2bf(acc[mi][j][1] + bias);
                pv.z = f2bf(acc[mi][j][2] + bias); pv.w = f2bf(acc[mi][j][3] + bias);
                const int t0 = tb + mi * 16 + quad * 4;
                *(ushort4*)(vT + ((size_t)b_ * HH + c) * TT + t0) = pv;
            }
        }
    }
}

// ---------------------------------------------------------------------------
// Kernel C (v15 = v14 + batch->XCD-pair swizzle).  Body byte-identical to
// the banked R14 winner (stride-72 staging, 2 barriers, setprio, LPT).
// ONLY change: index remap.  Diagnosis: FETCH_SIZE ~33.5MB vs ~8MB ideal
// (~4x over-fetch) -- each batch's K/V panels are 4MB (one XCD L2), but
// default round-robin dispatch spreads every batch over all 8 XCDs while
// ~2.5 batches are co-resident -> each XCD touches ~10MB -> L2 thrash ->
// staging loads pay L3/HBM latency.  Remap: xcd = blockIdx&7 (the measured
// %8 round-robin), batch b = xcd>>1 -> each batch pinned to one XCD PAIR;
// remaining bits enumerate (tile,split) with LPT (heavy tiles first).
// Bijective; attn_combine untouched.  grid = 2048 x 256 thr.
// ---------------------------------------------------------------------------
__global__ __launch_bounds__(256)
void attn_mfma_kernel(const ushort* __restrict__ q, const ushort* __restrict__ k,
                      const ushort* __restrict__ vT,
                      float* __restrict__ partL, ushort* __restrict__ partO)
{
    __shared__ ushort ks[64 * 72];
    __shared__ ushort vs[64 * 72];        // [d][s] (from vT)
    __shared__ ushort ps[4][16 * 72];     // wave-private P

    const int tid = threadIdx.x, w = tid >> 6, lane = tid & 63;
    const int m = lane & 15, quad = lane >> 4;
    const int xcd = blockIdx.x & 7;               // measured %8 XCD round-robin
    const int pos = blockIdx.x >> 3;              // 0..255 dispatch position
    const int b = xcd >> 1;                       // batch pinned to XCD pair
    const int idx = (pos << 1) | (xcd & 1);       // 0..511 within batch
    const int split = idx & 7;
    const int tile = 63 - (idx >> 3);             // LPT: heavy tiles first
    const int job = (b << 6) | tile;
    const int pid = job * 8 + split;              // effective partial index
    const int i0 = tile * 64;
    const int nch = tile + 1;
    const int lo = (nch * split) >> 3, hi = (nch * (split + 1)) >> 3;

    const size_t qrow = ((size_t)b * TT + i0 + w * 16 + m) * HH;
    const uint4 aq0u = *(const uint4*)(q + qrow + quad * 8);
    const uint4 aq1u = *(const uint4*)(q + qrow + 32 + quad * 8);
    const short8 aq0 = *(const short8*)&aq0u;
    const short8 aq1 = *(const short8*)&aq1u;

    float lrow[4] = {0.f, 0.f, 0.f, 0.f};
    floatx4 oacc[4];
    #pragma unroll
    for (int nt = 0; nt < 4; ++nt) oacc[nt] = (floatx4){0.f, 0.f, 0.f, 0.f};

    const int iq0 = i0 + w * 16;
    for (int ch = lo; ch < hi; ++ch) {
        const int s0 = ch * 64;
        __syncthreads();
        const size_t kb = ((size_t)b * TT + s0) * HH;
        #pragma unroll
        for (int it = 0; it < 2; ++it) {
            const int t2 = it * 256 + tid;
            const int r = t2 >> 3, seg = t2 & 7;
            *(uint4*)(ks + r * 72 + seg * 8) = *(const uint4*)(k + kb + (size_t)r * HH + seg * 8);
            *(uint4*)(vs + r * 72 + seg * 8) = *(const uint4*)(vT + ((size_t)b * HH + r) * TT + s0 + seg * 8);
        }
        __syncthreads();

        floatx4 sc[4];
        __builtin_amdgcn_s_setprio(1);
        #pragma unroll
        for (int nt = 0; nt < 4; ++nt) {
            const short8 b0 = *(const short8*)(ks + (nt * 16 + m) * 72 + quad * 8);
            const short8 b1 = *(const short8*)(ks + (nt * 16 + m) * 72 + 32 + quad * 8);
            floatx4 s_ = (floatx4){0.f, 0.f, 0.f, 0.f};
            s_ = __builtin_amdgcn_mfma_f32_16x16x32_bf16(aq0, b0, s_, 0, 0, 0);
            s_ = __builtin_amdgcn_mfma_f32_16x16x32_bf16(aq1, b1, s_, 0, 0, 0);
            sc[nt] = s_;
        }
        __builtin_amdgcn_s_setprio(0);

        // fixed-max exp2-domain softmax.  p = 2^(s' - FIXMAX2); masked -> 0.
        const bool need_mask = (s0 + 63 > iq0);     // wave-uniform: diagonal chunk only
        #pragma unroll
        for (int r = 0; r < 4; ++r) {
            float t0 = sc[0][r] - FIXMAX2;
            float t1 = sc[1][r] - FIXMAX2;
            float t2 = sc[2][r] - FIXMAX2;
            float t3 = sc[3][r] - FIXMAX2;
            if (need_mask) {
                const int dlim = iq0 + quad * 4 + r - s0 - m;   // mask iff c*16 > dlim
                if (0  > dlim) t0 = -1e30f;
                if (16 > dlim) t1 = -1e30f;
                if (32 > dlim) t2 = -1e30f;
                if (48 > dlim) t3 = -1e30f;
            }
            const float p0 = __builtin_amdgcn_exp2f(t0);
            const float p1 = __builtin_amdgcn_exp2f(t1);
            const float p2 = __builtin_amdgcn_exp2f(t2);
            const float p3 = __builtin_amdgcn_exp2f(t3);
            lrow[r] += (p0 + p1) + (p2 + p3);
            ushort* pr = ps[w] + (quad * 4 + r) * 72;
            pr[m]      = f2bf(p0);
            pr[16 + m] = f2bf(p1);
            pr[32 + m] = f2bf(p2);
            pr[48 + m] = f2bf(p3);
        }

        // PV: A = P (LDS round-trip), B = vT rows
        __builtin_amdgcn_s_setprio(1);
        #pragma unroll
        for (int ks_ = 0; ks_ < 2; ++ks_) {
            const short8 ap = *(const short8*)(ps[w] + m * 72 + ks_ * 32 + quad * 8);
            #pragma unroll
            for (int nt = 0; nt < 4; ++nt) {
                const short8 bv_ = *(const short8*)(vs + (nt * 16 + m) * 72 + ks_ * 32 + quad * 8);
                oacc[nt] = __builtin_amdgcn_mfma_f32_16x16x32_bf16(ap, bv_, oacc[nt], 0, 0, 0);
            }
        }
        __builtin_amdgcn_s_setprio(0);
    }

    // reduce lrow across the 16 m-lanes (rows live in (quad, r))
    #pragma unroll
    for (int r = 0; r < 4; ++r) {
        float s = lrow[r];
        s += __shfl_xor(s, 1); s += __shfl_xor(s, 2);
        s += __shfl_xor(s, 4); s += __shfl_xor(s, 8);
        lrow[r] = s;
    }
    if (m == 0) {
        #pragma unroll
        for (int r = 0; r < 4; ++r)
            partL[(size_t)pid * 64 + w * 16 + quad * 4 + r] = lrow[r];
    }
    ushort* po = partO + ((size_t)pid * 64 + w * 16) * 64;
    #pragma unroll
    for (int r = 0; r < 4; ++r) {
        const int row = quad * 4 + r;
        #pragma unroll
        for (int nt = 0; nt < 4; ++nt)
            po[row * 64 + nt * 16 + m] = f2bf(oacc[nt][r]);
    }
}

// ---------------------------------------------------------------------------
// Kernel D (v2, unchanged): combine 8 split partials (shared fixed
// max -> plain sums).  grid = 256 (job), 256 threads.
// ---------------------------------------------------------------------------
__global__ __launch_bounds__(256)
void attn_combine_kernel(const float* __restrict__ partL,
                         const ushort* __restrict__ partO, float* __restrict__ out)
{
    const int job = blockIdx.x;
    const int tid = threadIdx.x;
    const int row = tid >> 2, dq = tid & 3;

    float L = 0.f;
    #pragma unroll
    for (int s = 0; s < 8; ++s) L += partL[(size_t)(job * 8 + s) * 64 + row];
    const float inv = 1.f / L;

    float o[16];
    #pragma unroll
    for (int i = 0; i < 16; ++i) o[i] = 0.f;
    #pragma unroll
    for (int s = 0; s < 8; ++s) {
        const ushort* po = partO + (((size_t)(job * 8 + s) * 64 + row) * 64 + dq * 16);
        #pragma unroll
        for (int i2 = 0; i2 < 2; ++i2) {
            const ushort4 pa = *(const ushort4*)(po + i2 * 8);
            const ushort4 pb = *(const ushort4*)(po + i2 * 8 + 4);
            o[i2*8+0] += bf2f(pa.x); o[i2*8+1] += bf2f(pa.y);
            o[i2*8+2] += bf2f(pa.z); o[i2*8+3] += bf2f(pa.w);
            o[i2*8+4] += bf2f(pb.x); o[i2*8+5] += bf2f(pb.y);
            o[i2*8+6] += bf2f(pb.z); o[i2*8+7] += bf2f(pb.w);
        }
    }
    float4* dst = (float4*)(out + ((size_t)job * 64 + row) * 64 + dq * 16);
    #pragma unroll
    for (int i = 0; i < 4; ++i) {
        float4 v; v.x = o[i*4]*inv; v.y = o[i*4+1]*inv; v.z = o[i*4+2]*inv; v.w = o[i*4+3]*inv;
        dst[i] = v;
    }
}

extern "C" void kernel_launch(void* const* d_in, const int* in_sizes, int n_in,
                              void* d_out, int out_size, void* d_ws, size_t ws_size,
                              hipStream_t stream) {
    (void)in_sizes; (void)n_in; (void)out_size; (void)ws_size;
    const float* x  = (const float*)d_in[0];
    // d_in[1] = causal mask, structural -> unused
    const float* Wq = (const float*)d_in[2];
    const float* bq = (const float*)d_in[3];
    const float* Wk = (const float*)d_in[4];
    const float* bk = (const float*)d_in[5];
    const float* Wv = (const float*)d_in[6];
    const float* bv = (const float*)d_in[7];
    float* out = (float*)d_out;

    char* ws = (char*)d_ws;
    ushort* wTf   = (ushort*)ws;                          // 384 KB @ 0
    ushort* qb    = (ushort*)(ws + 393216);               // 2 MB
    ushort* kb    = qb + (size_t)BB * TT * HH;            // 2 MB
    ushort* vTb   = kb + (size_t)BB * TT * HH;            // 2 MB
    float*  partL = (float*) (ws + 6684672);              // 512 KB (2048*64*4)
    ushort* partO = (ushort*)(ws + 7208960);              // 16.8 MB (total ~24 MB)

    wtrans_kernel   <<<16, 256, 0, stream>>>(Wq, Wk, Wv, wTf);
    qkv_mfma_kernel <<<(BB * TT) / 32, 256, 0, stream>>>(x, wTf, bq, bk, bv, qb, kb, vTb);
    attn_mfma_kernel<<<BB * 64 * 8, 256, 0, stream>>>(qb, kb, vTb, partL, partO);
    attn_combine_kernel<<<BB * 64, 256, 0, stream>>>(partL, partO, out);
}

// Round 16
// 183.716 us; speedup vs baseline: 1.0550x; 1.0168x over previous
//
#include <hip/hip_runtime.h>
#include <hip/hip_bf16.h>

#define BB 4
#define TT 4096
#define CC 1024
#define HH 64

// q is pre-scaled by 0.125*log2(e) at projection time; attn works in exp2 domain.
#define QSCALE 0.18033688011112042f
#define FIXMAX2 23.083120654223414f    // 16 * log2(e)

typedef __attribute__((ext_vector_type(8))) short short8;   // 8 x bf16 (4 VGPRs)
typedef __attribute__((ext_vector_type(8))) ushort ushortx8;
typedef __attribute__((ext_vector_type(4))) float floatx4;  // MFMA C/D

__device__ __forceinline__ ushort f2bf(float f) {
    union { float f; unsigned u; } a; a.f = f;
    const unsigned u = a.u;
    return (ushort)((u + 0x7fffu + ((u >> 16) & 1u)) >> 16);   // RNE
}
__device__ __forceinline__ float bf2f(ushort h) {
    union { unsigned u; float f; } a; a.u = ((unsigned)h) << 16; return a.f;
}

// ---------------------------------------------------------------------------
// Kernel A (v2): W [1024 x 64] f32 x3 -> wTf fragment-major bf16:
// wTf[(kc*24 + ks*12 + w*3 + j)*512 + lane*8 + e].  grid = 16 x 256.
// ---------------------------------------------------------------------------
__global__ __launch_bounds__(256)
void wtrans_kernel(const float* __restrict__ Wq, const float* __restrict__ Wk,
                   const float* __restrict__ Wv, ushort* __restrict__ wTf)
{
    const int tid = threadIdx.x;
    const int kc = blockIdx.x;
    #pragma unroll
    for (int it = 0; it < 6; ++it) {
        const int s = it * 256 + tid;           // slot id in [0, 1536)
        const int lane = s & 63;
        const int t = s >> 6;                   // (ks*4 + w)*3 + j
        const int j = t % 3;
        const int qv = t / 3;                   // ks*4 + w
        const int wv = qv & 3, ks = qv >> 2;
        const int r = wv * 48 + j * 16 + (lane & 15);
        const int mat = r >> 6, n = r & 63;
        const int k0 = kc * 64 + ks * 32 + (lane >> 4) * 8;
        const float* W = (mat == 0) ? Wq : (mat == 1) ? Wk : Wv;
        ushortx8 o;
        #pragma unroll
        for (int e = 0; e < 8; ++e)
            o[e] = f2bf(W[(size_t)(k0 + e) * 64 + n]);
        *(ushortx8*)(wTf + ((size_t)(kc * 24 + t) * 64 + lane) * 8) = o;
    }
}

// ---------------------------------------------------------------------------
// Kernel B (v16): v10 body with WAVE-GROUP K-SPLIT.  Diagnosis: grid 512 =
// 2 blocks/CU, 8 waves/CU; 16 serial barrier-drain chunks with minimal TLP.
// Pipelining levers all falsified (R2/R4/R9); the chain LENGTH was never
// attacked.  Block = 512 thr (8 waves): waves 0-3 (kh=0) do K-chunks 0..7,
// waves 4-7 (kh=1) do chunks 8..15 concurrently.  Chain 16 -> 8 drains,
// waves/CU 8 -> 16, per-wave body identical to v10 (same regalloc).
// Final LDS reduce (24.6KB, after main loop) sums halves before the
// unchanged epilogue.  LDS = 18KB xs + 24.6KB red = 43KB (2 blocks/CU ok).
// ---------------------------------------------------------------------------
__global__ __launch_bounds__(512)
void qkv_mfma_kernel(const float* __restrict__ x, const ushort* __restrict__ wTf,
                     const float* __restrict__ bq, const float* __restrict__ bk,
                     const float* __restrict__ bv,
                     ushort* __restrict__ q, ushort* __restrict__ k,
                     ushort* __restrict__ vT)
{
    __shared__ ushort xs[2][2][32 * 72];     // [buf][k-half][row][col+pad]
    __shared__ float red[4 * 64 * 6 * 4];    // 24.6 KB cross-half reduce

    const int tid = threadIdx.x, w = tid >> 6, lane = tid & 63;
    const int wn = w & 3, kh = w >> 2;       // N-wave role, K-half
    const int m = lane & 15, quad = lane >> 4;
    const int row0 = blockIdx.x * 32;

    floatx4 acc[2][3];
    #pragma unroll
    for (int mi = 0; mi < 2; ++mi)
        #pragma unroll
        for (int j = 0; j < 3; ++j) acc[mi][j] = (floatx4){0.f, 0.f, 0.f, 0.f};

    // B-frag base: wave (kh, wn), chunk c -> global kc = kh*8 + c
    const ushort* gb = wTf + (size_t)wn * 1536 + lane * 8 + (size_t)kh * 8 * 12288;

    // x stage coords: thread stages row (tid>>4), half (tid>>3)&1, seg tid&7
    const int xr = tid >> 4, khs = (tid >> 3) & 1, xseg = tid & 7;
    const float* gx = x + (size_t)(row0 + xr) * CC + khs * 512 + xseg * 8;

    short8 bcur[3][2], bnxt[3][2];

    // ---- prologue: B-frags + x for iteration 0 ----
    #pragma unroll
    for (int j = 0; j < 3; ++j)
        #pragma unroll
        for (int ks_ = 0; ks_ < 2; ++ks_)
            bcur[j][ks_] = *(const short8*)(gb + ks_ * 6144 + j * 512);
    {
        const float4 xa = *(const float4*)(gx);
        const float4 xb = *(const float4*)(gx + 4);
        ushortx8 p;
        p[0] = f2bf(xa.x); p[1] = f2bf(xa.y); p[2] = f2bf(xa.z); p[3] = f2bf(xa.w);
        p[4] = f2bf(xb.x); p[5] = f2bf(xb.y); p[6] = f2bf(xb.z); p[7] = f2bf(xb.w);
        *(ushortx8*)(&xs[0][khs][xr * 72 + xseg * 8]) = p;
    }
    __syncthreads();

    for (int c = 0; c < 8; ++c) {
        const int cur = c & 1;
        // ---- prefetch iteration c+1: x first (HBM/L3), then B (L2) ----
        float4 na, nb;
        if (c < 7) {
            const int k0n = (c + 1) * 64;
            na = *(const float4*)(gx + k0n);
            nb = *(const float4*)(gx + k0n + 4);
            const ushort* gn = gb + (size_t)(c + 1) * 12288;
            #pragma unroll
            for (int j = 0; j < 3; ++j)
                #pragma unroll
                for (int ks_ = 0; ks_ < 2; ++ks_)
                    bnxt[j][ks_] = *(const short8*)(gn + ks_ * 6144 + j * 512);
        }
        // ---- compute this wave's chunk from its half's buffer ----
        const ushort* xb_ = xs[cur][kh];
        #pragma unroll
        for (int mi = 0; mi < 2; ++mi) {
            const short8 a0 = *(const short8*)(xb_ + (mi * 16 + m) * 72 + quad * 8);
            const short8 a1 = *(const short8*)(xb_ + (mi * 16 + m) * 72 + 32 + quad * 8);
            #pragma unroll
            for (int j = 0; j < 3; ++j) {
                acc[mi][j] = __builtin_amdgcn_mfma_f32_16x16x32_bf16(a0, bcur[j][0], acc[mi][j], 0, 0, 0);
                acc[mi][j] = __builtin_amdgcn_mfma_f32_16x16x32_bf16(a1, bcur[j][1], acc[mi][j], 0, 0, 0);
            }
        }
        // ---- late half of x stage + B reg ping-pong ----
        if (c < 7) {
            ushortx8 p;
            p[0] = f2bf(na.x); p[1] = f2bf(na.y); p[2] = f2bf(na.z); p[3] = f2bf(na.w);
            p[4] = f2bf(nb.x); p[5] = f2bf(nb.y); p[6] = f2bf(nb.z); p[7] = f2bf(nb.w);
            *(ushortx8*)(&xs[cur ^ 1][khs][xr * 72 + xseg * 8]) = p;
            #pragma unroll
            for (int j = 0; j < 3; ++j) {
                bcur[j][0] = bnxt[j][0];
                bcur[j][1] = bnxt[j][1];
            }
        }
        __syncthreads();
    }

    // ---- cross-half reduction: kh=1 writes, kh=0 adds ----
    if (kh == 1) {
        #pragma unroll
        for (int mi = 0; mi < 2; ++mi)
            #pragma unroll
            for (int j = 0; j < 3; ++j)
                *(floatx4*)(red + (((wn * 64 + lane) * 6 + mi * 3 + j) << 2)) = acc[mi][j];
    }
    __syncthreads();
    if (kh == 1) return;
    #pragma unroll
    for (int mi = 0; mi < 2; ++mi)
        #pragma unroll
        for (int j = 0; j < 3; ++j)
            acc[mi][j] += *(const floatx4*)(red + (((wn * 64 + lane) * 6 + mi * 3 + j) << 2));

    // epilogue (v10, w -> wn).  C-layout: row = quad*4 + r, col = nt*16 + m.
    const int b_ = row0 >> 12, tb = row0 & (TT - 1);
    #pragma unroll
    for (int j = 0; j < 3; ++j) {
        const int nt = wn * 3 + j;
        const int mat = nt >> 2;
        const int c = (nt & 3) * 16 + m;
        const float bias = (mat == 0) ? bq[c] : (mat == 1) ? bk[c] : bv[c];
        #pragma unroll
        for (int mi = 0; mi < 2; ++mi) {
            const int gr0 = row0 + mi * 16 + quad * 4;
            if (mat == 0) {
                #pragma unroll
                for (int r = 0; r < 4; ++r)
                    q[(size_t)(gr0 + r) * HH + c] = f2bf((acc[mi][j][r] + bias) * QSCALE);
            } else if (mat == 1) {
                #pragma unroll
                for (int r = 0; r < 4; ++r)
                    k[(size_t)(gr0 + r) * HH + c] = f2bf(acc[mi][j][r] + bias);
            } else {
                ushort4 pv;
                pv.x = f2bf(acc[mi][j][0] + bias); pv.y = f2bf(acc[mi][j][1] + bias);
                pv.z = f2bf(acc[mi][j][2] + bias); pv.w = f2bf(acc[mi][j][3] + bias);
                const int t0 = tb + mi * 16 + quad * 4;
                *(ushort4*)(vT + ((size_t)b_ * HH + c) * TT + t0) = pv;
            }
        }
    }
}

// ---------------------------------------------------------------------------
// Kernel C (v15, byte-identical to R15 winner = v11 + LPT + batch->XCD-pair
// swizzle, banked at 186.8us total).  grid = 2048 x 256 thr.
// ---------------------------------------------------------------------------
__global__ __launch_bounds__(256)
void attn_mfma_kernel(const ushort* __restrict__ q, const ushort* __restrict__ k,
                      const ushort* __restrict__ vT,
                      float* __restrict__ partL, ushort* __restrict__ partO)
{
    __shared__ ushort ks[64 * 72];
    __shared__ ushort vs[64 * 72];        // [d][s] (from vT)
    __shared__ ushort ps[4][16 * 72];     // wave-private P

    const int tid = threadIdx.x, w = tid >> 6, lane = tid & 63;
    const int m = lane & 15, quad = lane >> 4;
    const int xcd = blockIdx.x & 7;               // measured %8 XCD round-robin
    const int pos = blockIdx.x >> 3;              // 0..255 dispatch position
    const int b = xcd >> 1;                       // batch pinned to XCD pair
    const int idx = (pos << 1) | (xcd & 1);       // 0..511 within batch
    const int split = idx & 7;
    const int tile = 63 - (idx >> 3);             // LPT: heavy tiles first
    const int job = (b << 6) | tile;
    const int pid = job * 8 + split;              // effective partial index
    const int i0 = tile * 64;
    const int nch = tile + 1;
    const int lo = (nch * split) >> 3, hi = (nch * (split + 1)) >> 3;

    const size_t qrow = ((size_t)b * TT + i0 + w * 16 + m) * HH;
    const uint4 aq0u = *(const uint4*)(q + qrow + quad * 8);
    const uint4 aq1u = *(const uint4*)(q + qrow + 32 + quad * 8);
    const short8 aq0 = *(const short8*)&aq0u;
    const short8 aq1 = *(const short8*)&aq1u;

    float lrow[4] = {0.f, 0.f, 0.f, 0.f};
    floatx4 oacc[4];
    #pragma unroll
    for (int nt = 0; nt < 4; ++nt) oacc[nt] = (floatx4){0.f, 0.f, 0.f, 0.f};

    const int iq0 = i0 + w * 16;
    for (int ch = lo; ch < hi; ++ch) {
        const int s0 = ch * 64;
        __syncthreads();
        const size_t kb = ((size_t)b * TT + s0) * HH;
        #pragma unroll
        for (int it = 0; it < 2; ++it) {
            const int t2 = it * 256 + tid;
            const int r = t2 >> 3, seg = t2 & 7;
            *(uint4*)(ks + r * 72 + seg * 8) = *(const uint4*)(k + kb + (size_t)r * HH + seg * 8);
            *(uint4*)(vs + r * 72 + seg * 8) = *(const uint4*)(vT + ((size_t)b * HH + r) * TT + s0 + seg * 8);
        }
        __syncthreads();

        floatx4 sc[4];
        __builtin_amdgcn_s_setprio(1);
        #pragma unroll
        for (int nt = 0; nt < 4; ++nt) {
            const short8 b0 = *(const short8*)(ks + (nt * 16 + m) * 72 + quad * 8);
            const short8 b1 = *(const short8*)(ks + (nt * 16 + m) * 72 + 32 + quad * 8);
            floatx4 s_ = (floatx4){0.f, 0.f, 0.f, 0.f};
            s_ = __builtin_amdgcn_mfma_f32_16x16x32_bf16(aq0, b0, s_, 0, 0, 0);
            s_ = __builtin_amdgcn_mfma_f32_16x16x32_bf16(aq1, b1, s_, 0, 0, 0);
            sc[nt] = s_;
        }
        __builtin_amdgcn_s_setprio(0);

        // fixed-max exp2-domain softmax.  p = 2^(s' - FIXMAX2); masked -> 0.
        const bool need_mask = (s0 + 63 > iq0);     // wave-uniform: diagonal chunk only
        #pragma unroll
        for (int r = 0; r < 4; ++r) {
            float t0 = sc[0][r] - FIXMAX2;
            float t1 = sc[1][r] - FIXMAX2;
            float t2 = sc[2][r] - FIXMAX2;
            float t3 = sc[3][r] - FIXMAX2;
            if (need_mask) {
                const int dlim = iq0 + quad * 4 + r - s0 - m;   // mask iff c*16 > dlim
                if (0  > dlim) t0 = -1e30f;
                if (16 > dlim) t1 = -1e30f;
                if (32 > dlim) t2 = -1e30f;
                if (48 > dlim) t3 = -1e30f;
            }
            const float p0 = __builtin_amdgcn_exp2f(t0);
            const float p1 = __builtin_amdgcn_exp2f(t1);
            const float p2 = __builtin_amdgcn_exp2f(t2);
            const float p3 = __builtin_amdgcn_exp2f(t3);
            lrow[r] += (p0 + p1) + (p2 + p3);
            ushort* pr = ps[w] + (quad * 4 + r) * 72;
            pr[m]      = f2bf(p0);
            pr[16 + m] = f2bf(p1);
            pr[32 + m] = f2bf(p2);
            pr[48 + m] = f2bf(p3);
        }

        // PV: A = P (LDS round-trip), B = vT rows
        __builtin_amdgcn_s_setprio(1);
        #pragma unroll
        for (int ks_ = 0; ks_ < 2; ++ks_) {
            const short8 ap = *(const short8*)(ps[w] + m * 72 + ks_ * 32 + quad * 8);
            #pragma unroll
            for (int nt = 0; nt < 4; ++nt) {
                const short8 bv_ = *(const short8*)(vs + (nt * 16 + m) * 72 + ks_ * 32 + quad * 8);
                oacc[nt] = __builtin_amdgcn_mfma_f32_16x16x32_bf16(ap, bv_, oacc[nt], 0, 0, 0);
            }
        }
        __builtin_amdgcn_s_setprio(0);
    }

    // reduce lrow across the 16 m-lanes (rows live in (quad, r))
    #pragma unroll
    for (int r = 0; r < 4; ++r) {
        float s = lrow[r];
        s += __shfl_xor(s, 1); s += __shfl_xor(s, 2);
        s += __shfl_xor(s, 4); s += __shfl_xor(s, 8);
        lrow[r] = s;
    }
    if (m == 0) {
        #pragma unroll
        for (int r = 0; r < 4; ++r)
            partL[(size_t)pid * 64 + w * 16 + quad * 4 + r] = lrow[r];
    }
    ushort* po = partO + ((size_t)pid * 64 + w * 16) * 64;
    #pragma unroll
    for (int r = 0; r < 4; ++r) {
        const int row = quad * 4 + r;
        #pragma unroll
        for (int nt = 0; nt < 4; ++nt)
            po[row * 64 + nt * 16 + m] = f2bf(oacc[nt][r]);
    }
}

// ---------------------------------------------------------------------------
// Kernel D (v2, unchanged): combine 8 split partials (shared fixed
// max -> plain sums).  grid = 256 (job), 256 threads.
// ---------------------------------------------------------------------------
__global__ __launch_bounds__(256)
void attn_combine_kernel(const float* __restrict__ partL,
                         const ushort* __restrict__ partO, float* __restrict__ out)
{
    const int job = blockIdx.x;
    const int tid = threadIdx.x;
    const int row = tid >> 2, dq = tid & 3;

    float L = 0.f;
    #pragma unroll
    for (int s = 0; s < 8; ++s) L += partL[(size_t)(job * 8 + s) * 64 + row];
    const float inv = 1.f / L;

    float o[16];
    #pragma unroll
    for (int i = 0; i < 16; ++i) o[i] = 0.f;
    #pragma unroll
    for (int s = 0; s < 8; ++s) {
        const ushort* po = partO + (((size_t)(job * 8 + s) * 64 + row) * 64 + dq * 16);
        #pragma unroll
        for (int i2 = 0; i2 < 2; ++i2) {
            const ushort4 pa = *(const ushort4*)(po + i2 * 8);
            const ushort4 pb = *(const ushort4*)(po + i2 * 8 + 4);
            o[i2*8+0] += bf2f(pa.x); o[i2*8+1] += bf2f(pa.y);
            o[i2*8+2] += bf2f(pa.z); o[i2*8+3] += bf2f(pa.w);
            o[i2*8+4] += bf2f(pb.x); o[i2*8+5] += bf2f(pb.y);
            o[i2*8+6] += bf2f(pb.z); o[i2*8+7] += bf2f(pb.w);
        }
    }
    float4* dst = (float4*)(out + ((size_t)job * 64 + row) * 64 + dq * 16);
    #pragma unroll
    for (int i = 0; i < 4; ++i) {
        float4 v; v.x = o[i*4]*inv; v.y = o[i*4+1]*inv; v.z = o[i*4+2]*inv; v.w = o[i*4+3]*inv;
        dst[i] = v;
    }
}

extern "C" void kernel_launch(void* const* d_in, const int* in_sizes, int n_in,
                              void* d_out, int out_size, void* d_ws, size_t ws_size,
                              hipStream_t stream) {
    (void)in_sizes; (void)n_in; (void)out_size; (void)ws_size;
    const float* x  = (const float*)d_in[0];
    // d_in[1] = causal mask, structural -> unused
    const float* Wq = (const float*)d_in[2];
    const float* bq = (const float*)d_in[3];
    const float* Wk = (const float*)d_in[4];
    const float* bk = (const float*)d_in[5];
    const float* Wv = (const float*)d_in[6];
    const float* bv = (const float*)d_in[7];
    float* out = (float*)d_out;

    char* ws = (char*)d_ws;
    ushort* wTf   = (ushort*)ws;                          // 384 KB @ 0
    ushort* qb    = (ushort*)(ws + 393216);               // 2 MB
    ushort* kb    = qb + (size_t)BB * TT * HH;            // 2 MB
    ushort* vTb   = kb + (size_t)BB * TT * HH;            // 2 MB
    float*  partL = (float*) (ws + 6684672);              // 512 KB (2048*64*4)
    ushort* partO = (ushort*)(ws + 7208960);              // 16.8 MB (total ~24 MB)

    wtrans_kernel   <<<16, 256, 0, stream>>>(Wq, Wk, Wv, wTf);
    qkv_mfma_kernel <<<(BB * TT) / 32, 512, 0, stream>>>(x, wTf, bq, bk, bv, qb, kb, vTb);
    attn_mfma_kernel<<<BB * 64 * 8, 256, 0, stream>>>(qb, kb, vTb, partL, partO);
    attn_combine_kernel<<<BB * 64, 256, 0, stream>>>(partL, partO, out);
}